// Round 16
// baseline (270.645 us; speedup 1.0000x reference)
//
#include <hip/hip_runtime.h>
#include <math.h>

#define NB 256
#define SEQ 65536
#define NP 2047
#define NPM 2046
#define NPP 2048   // x3 row stride (padded so rows are 16B-aligned for float4 loads)
#define KPAD 2048  // gemm K padded (bf16 operands zero-filled at k=2046,2047)
#define LEN1 2047
#define LEN2 1023
#define LEN3 511
#define C1 32
#define C2 64
#define C3 128
#define NPART 2048
#define NPART2 (NB*4)   // layer-2 partial count (dense stride — MUST match k_fin npart)
#define SROW 40     // conv2m LDS row stride (shorts): 80 B -> 16B-aligned rows, bank-spread
#define SROW3 72    // conv3 LDS row stride (shorts): 144 B -> 16B-aligned rows, bank-spread
#define PWIN 8288   // patch block x window: 256*32 + 96
#define PLDS (PWIN + PWIN/32 + 2)   // swizzled LDS size (idx = i + i/32)

// workspace offsets (floats). Region timeline:
//   Y2: Wb (bf16, dead after gemm) -> h1rB bf16 [b][m][i] raw pooled (conv1f out, dead after conv2m)
//   Y1: pmB bf16 [b][m][c] raw pooled conv2 out at OFF_PM (read by conv3s AND out3, bn2 applied on stage)
//   DMAX: dmax bf16 [b][KPAD]
#define OFF_X3   0
#define SZ_X3    (NB*3*NPP)
#define OFF_DMAX (OFF_X3 + SZ_X3)
#define SZ_DMAX  (NB*NPM)
#define OFF_Y1   (OFF_DMAX + SZ_DMAX)
#define SZ_Y1    (NB*C1*LEN1)
#define OFF_Y2   (OFF_Y1 + SZ_Y1)
#define SZ_Y2    (NB*C2*LEN2)
#define OFF_S1   (OFF_Y2 + SZ_Y2)
#define OFF_S2   (OFF_S1 + 2*C1)
#define OFF_S3   (OFF_S2 + 2*C2)
#define OFF_W2C  (OFF_S3 + 2*C3)
#define OFF_W3B  (OFF_W2C + C1*C2*3)   // conv3 weights bf16 [tap][c][i]
#define OFF_PS   (OFF_W3B + C2*C3*3)
#define OFF_PQ   (OFF_PS + C3*NPART)
#define OFF_WB   OFF_Y2   // gemm W bf16 [NP][KPAD] (dead after gemm)
#define OFF_H1R  OFF_Y2   // pooled raw conv1 bf16 [b][m][i] (dead after conv2m)
#define OFF_PM   (OFF_Y1 + 4300000)   // bf16 [b][m][c], m<LEN3 (8.37M shorts = 4.19M floats, fits)
#define OFF_W2B  OFF_W2C  // conv2 weights bf16 [tap][c=64][i=32]

typedef __attribute__((ext_vector_type(8))) short short8;
typedef __attribute__((ext_vector_type(4))) short short4v;
typedef __attribute__((ext_vector_type(4))) float f32x4;

__device__ inline short f2bf(float f){
  union { float f; unsigned u; } x; x.f = f;
  unsigned r = x.u + 0x7FFF + ((x.u >> 16) & 1);   // RNE; inputs are normal finite
  return (short)(r >> 16);
}
__device__ inline float bf2f(short s){
  union { unsigned u; float f; } x; x.u = ((unsigned)(unsigned short)s) << 16; return x.f;
}

#define RED4L(v) v += __shfl_xor(v,1,64); v += __shfl_xor(v,2,64); \
                 v += __shfl_xor(v,4,64); v += __shfl_xor(v,8,64);

// MFMA tile grid: (lt, ct) in 4x4
#define TILES(X) X(0,0) X(0,1) X(0,2) X(0,3) X(1,0) X(1,1) X(1,2) X(1,3) \
                 X(2,0) X(2,1) X(2,2) X(2,3) X(3,0) X(3,1) X(3,2) X(3,3)
#define DECLBIAS(P,ct) f32x4 bi##ct = *(const f32x4*)((P) + cbase + ct*16 + kq*4);
#define DECLACC(lt,ct) f32x4 acc##lt##ct = bi##ct;

// ---------------- K1: merged patch v3 (LDS-staged, shuffle-free) + prep (weight packs) ----------------
// R16: patch branch rewritten — R0 version was shfl-latency-bound (~25us vs 10.6 HBM floor).
// Block = 256 patches; x window coalesced into swizzled LDS (idx=i+i/32, conflict-free);
// each thread computes its patch's mean/std/dmax from 96 LDS reads + ring buffer. No shuffles.
__global__ __launch_bounds__(256) void k_pp(const float* __restrict__ x, const float* __restrict__ c1b,
                                            const float* __restrict__ W, const float* __restrict__ w2,
                                            const float* __restrict__ w3, float* __restrict__ ws){
  int bid = blockIdx.x;
  if (bid < 8*NB){
    float* x3    = ws + OFF_X3;
    short* dmaxB = (short*)(ws + OFF_DMAX);   // bf16 [NB][KPAD], zero-padded k>=NPM
    int b   = bid >> 3;
    int blk = bid & 7;
    int P0  = blk*256;                        // patches P0..P0+255
    __shared__ float xs[PLDS];
    const float* xb = x + (size_t)b*SEQ + (size_t)P0*32;
    int lim = SEQ - P0*32;                    // valid floats in window (blk=7: 8192 < PWIN)
    for (int u = threadIdx.x; u < PWIN/4; u += 256){
      int i0 = u*4;
      float4 v;
      if (i0 + 4 <= lim){
        v = *(const float4*)(xb + i0);
      } else {
        float t0 = (i0+0 < lim) ? xb[i0+0] : 0.f;
        float t1 = (i0+1 < lim) ? xb[i0+1] : 0.f;
        float t2 = (i0+2 < lim) ? xb[i0+2] : 0.f;
        float t3 = (i0+3 < lim) ? xb[i0+3] : 0.f;
        v = make_float4(t0,t1,t2,t3);
      }
      int i;
      i = i0+0; xs[i + (i>>5)] = v.x;
      i = i0+1; xs[i + (i>>5)] = v.y;
      i = i0+2; xs[i + (i>>5)] = v.z;
      i = i0+3; xs[i + (i>>5)] = v.w;
    }
    __syncthreads();
    int t = threadIdx.x;
    int p = P0 + t;
    // patch p: stats over w[0..63] = x[32p..32p+63]; dmax = max_k (w[k+32] - w[k]), k=0..63
    float ring[32];
    float s = 0.f, q = 0.f, d = -1e30f;
    #pragma unroll
    for (int j=0;j<96;j++){
      float v = xs[33*t + j + (j>>5)];        // idx(32t+j) = 33t + j + (j>>5)
      if (j < 64){ s += v; q = fmaf(v, v, q); }
      if (j >= 32){ d = fmaxf(d, v - ring[j & 31]); }
      ring[j & 31] = v;
    }
    if (p < NP){
      float mean = s*(1.0f/64.0f);
      float var  = (q - s*mean)*(1.0f/63.0f);   // ddof=1
      x3[(size_t)(b*3+0)*NPP + p] = mean;
      x3[(size_t)(b*3+1)*NPP + p] = sqrtf(fmaxf(var,0.0f));
      x3[(size_t)(b*3+2)*NPP + p] = c1b[p];     // bias init (gemm atomically adds on top)
    }
    dmaxB[(size_t)b*KPAD + p] = (p < NPM) ? f2bf(d) : (short)0;
  } else {
    // ---- prep branch ----
    int pb = bid - 8*NB;
    if (pb < 8*NP){
      short* Wb = (short*)(ws + OFF_WB);
      int o = pb >> 3;
      int k = (pb & 7)*256 + threadIdx.x;
      Wb[(size_t)o*KPAD + k] = (k < NPM) ? f2bf(W[(size_t)o*NPM + k]) : (short)0;
    } else {
      short* w2b = (short*)(ws + OFF_W2B);
      short* w3b = (short*)(ws + OFF_W3B);
      int t = (pb - 8*NP)*256 + threadIdx.x;
      if (t < 3*C2*C1){                        // 6144
        int tap = t / (C2*C1);
        int r = t - tap*(C2*C1);
        int c = r >> 5, i = r & 31;
        w2b[t] = f2bf(w2[(c*C1 + i)*3 + tap]); // w2b[(tap*C2+c)*C1+i]
      }
      if (t < 3*C3*C2){                        // 24576
        int tap = t / (C3*C2);
        int r = t - tap*(C3*C2);
        int c = r / C2, i = r - c*C2;
        w3b[(tap*C3 + c)*C2 + i] = f2bf(w3[(c*C2+i)*3 + tap]);
      }
    }
  }
}

// ---------------- K2: d2[b,o] += sum_k dmax[b,k]*W[o,k] via MFMA bf16 ----------------
// R16: K-split widened 4 -> 8 (512 blocks = 2/CU; shorter per-block MFMA chains).
__global__ __launch_bounds__(256) void k_gemm(float* __restrict__ ws){
  const short* Ab = (const short*)(ws + OFF_DMAX); // [NB][KPAD]
  const short* Bb = (const short*)(ws + OFF_WB);   // [NP][KPAD]
  float* x3 = ws + OFF_X3;
  int wid  = __builtin_amdgcn_readfirstlane(threadIdx.x >> 6);
  int lane = threadIdx.x & 63;
  int ln = lane & 15, kq = lane >> 4;
  int n0  = blockIdx.x*32;                 // o tile pair base
  int ks  = blockIdx.y*256;                // K split (8 steps of 32)
  f32x4 acc[4][2];
  #pragma unroll
  for (int bt=0;bt<4;bt++){ acc[bt][0] = (f32x4){0.f,0.f,0.f,0.f}; acc[bt][1] = (f32x4){0.f,0.f,0.f,0.f}; }
  int o0 = n0 + ln, o1 = n0 + 16 + ln;
  const short* ap  = Ab + (size_t)(wid*16 + ln)*KPAD + ks + kq*8;   // + bt*64*KPAD
  const short* bp0 = Bb + (size_t)min(o0, NP-1)*KPAD + ks + kq*8;
  const short* bp1 = Bb + (size_t)min(o1, NP-1)*KPAD + ks + kq*8;
  #pragma unroll 2
  for (int s=0; s<8; s++){
    short8 b0 = *(const short8*)(bp0 + s*32);
    short8 b1 = *(const short8*)(bp1 + s*32);
    #pragma unroll
    for (int bt=0;bt<4;bt++){
      short8 av = *(const short8*)(ap + (size_t)bt*64*KPAD + s*32);
      acc[bt][0] = __builtin_amdgcn_mfma_f32_16x16x32_bf16(av, b0, acc[bt][0], 0, 0, 0);
      acc[bt][1] = __builtin_amdgcn_mfma_f32_16x16x32_bf16(av, b1, acc[bt][1], 0, 0, 0);
    }
  }
  // D[row=kq*4+r][col=ln]: row -> b offset, col -> o offset
  #pragma unroll
  for (int bt=0;bt<4;bt++){
    #pragma unroll
    for (int r=0;r<4;r++){
      int b = bt*64 + wid*16 + kq*4 + r;
      float* xp = x3 + ((size_t)(b*3) + 2)*NPP;
      if (o0 < NP) atomicAdd(xp + o0, acc[bt][0][r]);
      if (o1 < NP) atomicAdd(xp + o1, acc[bt][1][r]);
    }
  }
}

// ---------------- K3: conv1f (3->32, k=5, pad=2) + fused BN1 stats + fused maxpool ----------------
// pooled raw output stored bf16 (h1rB) — halves the h1 round-trip (stats still from fp32 accs).
__global__ __launch_bounds__(256) void k_conv1f(const float* __restrict__ w1, const float* __restrict__ b1, float* __restrict__ ws){
  const float* x3 = ws + OFF_X3;
  short* h1rB = (short*)(ws + OFF_H1R);  // bf16 raw pooled [b][m][c], m<LEN2
  float* ps = ws + OFF_PS;
  float* pq = ws + OFF_PQ;
  int b = blockIdx.y;
  int blk = blockIdx.x;                 // 0..7 (256 positions per block)
  int w = threadIdx.x >> 6;             // wave 0..3 (64 positions)
  int lane = threadIdx.x & 63;
  int h = lane >> 5, c = lane & 31;     // half-wave position block, channel
  int p0 = blk*256 + w*64 + h*32;       // this lane's 32 positions: p0..p0+31
  float wv[3][5];
  #pragma unroll
  for (int i=0;i<3;i++){
    #pragma unroll
    for (int j=0;j<5;j++) wv[i][j] = w1[(c*3+i)*5+j];
  }
  float bc = b1[c];
  const float* xb = x3 + (size_t)b*3*NPP;
  float s = 0.f, q = 0.f;
  #pragma unroll
  for (int k0=0;k0<32;k0+=8){
    int base = p0 + k0 - 4;             // multiple of 4 (may be -4 at the very start)
    float xw[3][16];
    #pragma unroll
    for (int i=0;i<3;i++){
      const float* xr = xb + (size_t)i*NPP;
      if (base >= 0 && base + 16 <= LEN1){
        #pragma unroll
        for (int t=0;t<4;t++) *(f32x4*)&xw[i][4*t] = *(const f32x4*)(xr + base + 4*t);
      } else {
        #pragma unroll
        for (int t=0;t<16;t++){ int g = base + t; xw[i][t] = (g >= 0 && g < LEN1) ? xr[g] : 0.f; }
      }
    }
    float acc[8];
    #pragma unroll
    for (int k=0;k<8;k++){
      float a = bc;
      #pragma unroll
      for (int i=0;i<3;i++){
        #pragma unroll
        for (int j=0;j<5;j++) a = fmaf(wv[i][j], xw[i][k+j+2], a);   // g = p0+k0+k+j-2 -> t=k+j+2
      }
      acc[k] = a;
      if (p0 + k0 + k < LEN1){ s += a; q = fmaf(a, a, q); }   // stats over UNPOOLED y1
    }
    #pragma unroll
    for (int t=0;t<4;t++){
      int m = ((p0 + k0) >> 1) + t;
      if (m < LEN2) h1rB[((size_t)b*LEN2 + m)*C1 + c] = f2bf(fmaxf(acc[2*t], acc[2*t+1]));
    }
  }
  s += __shfl_xor(s, 32, 64);
  q += __shfl_xor(q, 32, 64);
  __shared__ float es[4][C1], eq[4][C1];
  if (h == 0){ es[w][c] = s; eq[w][c] = q; }
  __syncthreads();
  if (threadIdx.x < C1){
    int cc = threadIdx.x;
    float S = es[0][cc]+es[1][cc]+es[2][cc]+es[3][cc];
    float Q = eq[0][cc]+eq[1][cc]+eq[2][cc]+eq[3][cc];
    ps[(size_t)cc*NPART + b*8 + blk] = S;
    pq[(size_t)cc*NPART + b*8 + blk] = Q;
  }
}

// ---------------- finalize BN from partials (+ optional out-zeroing for layer 3) ----------------
__global__ __launch_bounds__(256) void k_fin(const float* __restrict__ ps, const float* __restrict__ pq,
                                             const float* __restrict__ g, const float* __restrict__ be,
                                             float* __restrict__ stats, int C, int npart, double invN,
                                             float* __restrict__ outz){
  if (outz) outz[(size_t)threadIdx.x * C3 + blockIdx.x] = 0.f;  // layer-3: 128 blocks x 256 thr = NB*C3
  int c = blockIdx.x;
  double s=0.0, q=0.0;
  for (int j=threadIdx.x; j<npart; j+=256){ s += (double)ps[c*npart+j]; q += (double)pq[c*npart+j]; }
  #pragma unroll
  for (int off=32; off; off>>=1){ s += __shfl_xor(s,off,64); q += __shfl_xor(q,off,64); }
  __shared__ double rs[4], rq[4];
  int wid = threadIdx.x>>6, lane=threadIdx.x&63;
  if (lane==0){ rs[wid]=s; rq[wid]=q; }
  __syncthreads();
  if (threadIdx.x==0){
    double S = rs[0]+rs[1]+rs[2]+rs[3];
    double Q = rq[0]+rq[1]+rq[2]+rq[3];
    double mean = S*invN;
    double var  = Q*invN - mean*mean;
    double a = (double)g[c] / sqrt(var + 1e-5);
    stats[c]   = (float)a;
    stats[C+c] = (float)((double)be[c] - mean*a);
  }
}

// ---------------- K5: conv2m — LDS-staged h1 tile (bn1 applied to bf16 input); pmax stored bf16 ----------------
__global__ __launch_bounds__(256) void k_conv2m(const float* __restrict__ b2, float* __restrict__ ws){
  const short* h1rB = (const short*)(ws + OFF_H1R); // bf16 [b][m][C1] raw pooled
  const float* st1 = ws + OFF_S1;                   // bn1 a[32], b[32]
  const short* w2b = (const short*)(ws + OFF_W2B);  // [tap][C2][C1]
  short* pmB = (short*)(ws + OFF_PM);               // bf16 [b][m][c], m<LEN3 (raw pooled, pre-bn2)
  float* ps = ws + OFF_PS;
  float* pq = ws + OFF_PQ;
  int b   = blockIdx.y;
  int blk = blockIdx.x;                // 0..3 (256 positions each)
  int l0  = blk*256;
  __shared__ __align__(16) short sh[258*SROW];
  // ---- stage: 258 rows x 4 groups(8ch); consecutive threads -> consecutive 16B chunks (coalesced)
  for (int u = threadIdx.x; u < 258*4; u += 256){
    int row = u >> 2, g = u & 3;
    int pos = l0 - 1 + row;
    short8 r8 = (short8)0;
    if (pos >= 0 && pos < LEN2){
      short8 xv = *(const short8*)(h1rB + ((size_t)b*LEN2 + pos)*C1 + g*8);
      f32x4 alo = *(const f32x4*)(st1 + g*8),      ahi = *(const f32x4*)(st1 + g*8 + 4);
      f32x4 blo = *(const f32x4*)(st1 + C1 + g*8), bhi = *(const f32x4*)(st1 + C1 + g*8 + 4);
      #pragma unroll
      for (int j=0;j<4;j++){
        r8[j]   = f2bf(fmaxf(fmaf(alo[j], bf2f(xv[j]),   blo[j]), 0.f));
        r8[j+4] = f2bf(fmaxf(fmaf(ahi[j], bf2f(xv[j+4]), bhi[j]), 0.f));
      }
    }
    *(short8*)(sh + row*SROW + g*8) = r8;
  }
  __syncthreads();
  int w   = __builtin_amdgcn_readfirstlane(threadIdx.x >> 6);
  int lane = threadIdx.x & 63;
  int ln = lane & 15, kq = lane >> 4;
  int lw = l0 + w*64;                  // wave's position base; l = lw + lt*16 + ln
  int cbase = 0;
  DECLBIAS(b2,0) DECLBIAS(b2,1) DECLBIAS(b2,2) DECLBIAS(b2,3)
  TILES(DECLACC)
  // preload 12 A fragments (tap x ct)
  const short* wA = w2b + (size_t)ln*C1 + kq*8;
#define LDW(T,ct) short8 aw##T##ct = *(const short8*)(wA + (size_t)(T*C2 + ct*16)*C1);
  LDW(0,0) LDW(0,1) LDW(0,2) LDW(0,3)
  LDW(1,0) LDW(1,1) LDW(1,2) LDW(1,3)
  LDW(2,0) LDW(2,1) LDW(2,2) LDW(2,3)
#undef LDW
#define MMT0(lt,ct) acc##lt##ct = __builtin_amdgcn_mfma_f32_16x16x32_bf16(aw0##ct, bv##lt, acc##lt##ct, 0, 0, 0);
#define MMT1(lt,ct) acc##lt##ct = __builtin_amdgcn_mfma_f32_16x16x32_bf16(aw1##ct, bv##lt, acc##lt##ct, 0, 0, 0);
#define MMT2(lt,ct) acc##lt##ct = __builtin_amdgcn_mfma_f32_16x16x32_bf16(aw2##ct, bv##lt, acc##lt##ct, 0, 0, 0);
#define LDB2(lt,T) short8 bv##lt = *(const short8*)(sh + (size_t)(w*64 + lt*16 + T + ln)*SROW + kq*8);
#define CSTEP(T) { LDB2(0,T) LDB2(1,T) LDB2(2,T) LDB2(3,T) TILES(MMT##T) }
  CSTEP(0) CSTEP(1) CSTEP(2)
#undef CSTEP
#undef LDB2
  // pool (lane pairs along ln) + store bf16 short4 at [b][m][ct*16+kq*4]
#define PST(lt,ct) { \
    float p0_ = fmaxf(acc##lt##ct[0], __shfl_xor(acc##lt##ct[0],1,64)); \
    float p1_ = fmaxf(acc##lt##ct[1], __shfl_xor(acc##lt##ct[1],1,64)); \
    float p2_ = fmaxf(acc##lt##ct[2], __shfl_xor(acc##lt##ct[2],1,64)); \
    float p3_ = fmaxf(acc##lt##ct[3], __shfl_xor(acc##lt##ct[3],1,64)); \
    int l_ = lw + lt*16 + ln; \
    if (!(ln & 1) && (l_ >> 1) < LEN3){ \
      short4v pv_ = { f2bf(p0_), f2bf(p1_), f2bf(p2_), f2bf(p3_) }; \
      *(short4v*)(pmB + ((size_t)b*LEN3 + (l_>>1))*C2 + ct*16 + kq*4) = pv_; } }
  TILES(PST)
#undef PST
  // fused stats over unpooled positions (mask l<LEN2)
  __shared__ float es[4][C2], eq[4][C2];
  #pragma unroll
  for (int ct=0;ct<4;ct++){
    float s0=0.f,s1=0.f,s2=0.f,s3=0.f,q0=0.f,q1=0.f,q2=0.f,q3=0.f;
#define ACCST(lt,CT) if (CT == ct){ int l_ = lw + lt*16 + ln; if (l_ < LEN2){ \
      s0 += acc##lt##CT[0]; q0 = fmaf(acc##lt##CT[0], acc##lt##CT[0], q0); \
      s1 += acc##lt##CT[1]; q1 = fmaf(acc##lt##CT[1], acc##lt##CT[1], q1); \
      s2 += acc##lt##CT[2]; q2 = fmaf(acc##lt##CT[2], acc##lt##CT[2], q2); \
      s3 += acc##lt##CT[3]; q3 = fmaf(acc##lt##CT[3], acc##lt##CT[3], q3); } }
    TILES(ACCST)
#undef ACCST
    RED4L(s0) RED4L(s1) RED4L(s2) RED4L(s3)
    RED4L(q0) RED4L(q1) RED4L(q2) RED4L(q3)
    if (ln == 0){
      int c0 = ct*16 + kq*4;
      es[w][c0+0]=s0; es[w][c0+1]=s1; es[w][c0+2]=s2; es[w][c0+3]=s3;
      eq[w][c0+0]=q0; eq[w][c0+1]=q1; eq[w][c0+2]=q2; eq[w][c0+3]=q3;
    }
  }
  __syncthreads();
  if (threadIdx.x < C2){
    int c = threadIdx.x;
    float S = es[0][c]+es[1][c]+es[2][c]+es[3][c];
    float Q = eq[0][c]+eq[1][c]+eq[2][c]+eq[3][c];
    ps[(size_t)c*NPART2 + b*4 + blk] = S;
    pq[(size_t)c*NPART2 + b*4 + blk] = Q;
  }
}

// ---- shared staging for conv3s/out3: pmB window -> LDS bf16 [130][SROW3], bn2+relu+f2bf fused ----
#define STAGE3(SH, BB, L0BLK) \
  for (int u = threadIdx.x; u < 130*8; u += 256){ \
    int row_ = u >> 3, g_ = u & 7; \
    int pos_ = (L0BLK) - 1 + row_; \
    short8 r8_ = (short8)0; \
    if (pos_ >= 0 && pos_ < LEN3){ \
      short8 xm_ = *(const short8*)(pmB + ((size_t)(BB)*LEN3 + pos_)*C2 + g_*8); \
      f32x4 alo_ = *(const f32x4*)(st2 + g_*8),      ahi_ = *(const f32x4*)(st2 + g_*8 + 4); \
      f32x4 blo_ = *(const f32x4*)(st2 + C2 + g_*8), bhi_ = *(const f32x4*)(st2 + C2 + g_*8 + 4); \
      _Pragma("unroll") \
      for (int j=0;j<4;j++){ \
        r8_[j]   = f2bf(fmaxf(fmaf(alo_[j], bf2f(xm_[j]),   blo_[j]), 0.f)); \
        r8_[j+4] = f2bf(fmaxf(fmaf(ahi_[j], bf2f(xm_[j+4]), bhi_[j]), 0.f)); \
      } \
    } \
    *(short8*)(SH + (size_t)row_*SROW3 + g_*8) = r8_; \
  }

// ---------------- K7: conv3 via MFMA bf16 — STATS ONLY; h2 built on-the-fly from pmB ----------------
__global__ __launch_bounds__(256) void k_conv3s(const float* __restrict__ b3, float* __restrict__ ws){
  const short* pmB = (const short*)(ws + OFF_PM);   // bf16 [b][m][C2] raw pooled
  const float* st2 = ws + OFF_S2;
  const short* w3b = (const short*)(ws + OFF_W3B);  // [tap][C3][C2]
  float* ps = ws + OFF_PS;
  float* pq = ws + OFF_PQ;
  int b   = blockIdx.y;
  int blk = blockIdx.x;                // 0..3 (128 positions)
  int l0blk = blk*128;
  __shared__ __align__(16) short sh[130*SROW3];
  STAGE3(sh, b, l0blk)
  __syncthreads();
  int wid = __builtin_amdgcn_readfirstlane(threadIdx.x >> 6);
  int lane = threadIdx.x & 63;
  int ln = lane & 15, kq = lane >> 4;
  int lh = wid & 1, ch = wid >> 1;     // wave-uniform
  int l0 = l0blk + lh*64;              // l = l0 + lt*16 + ln
  int cbase = ch*64;                   // A-row c = cbase+ct*16+ln; D-row c = cbase+ct*16+kq*4+r
  DECLBIAS(b3,0) DECLBIAS(b3,1) DECLBIAS(b3,2) DECLBIAS(b3,3)
  TILES(DECLACC)
  // fragment (lt,t,s): LDS row = lh*64 + lt*16 + ln + t ; ch = s*32 + kq*8
  const short* hL = sh + (size_t)(lh*64 + ln)*SROW3 + kq*8;
  const short* wA = w3b + (size_t)(cbase + ln)*C2 + kq*8;        // + (t*C3 + ct*16)*C2 + s*32
  #pragma unroll
  for (int t=0;t<3;t++){
    #pragma unroll
    for (int s=0;s<2;s++){
#define LDB(lt) short8 bv##lt = *(const short8*)(hL + (size_t)(lt*16 + t)*SROW3 + s*32);
      LDB(0) LDB(1) LDB(2) LDB(3)
#define LDA(ct) short8 av##ct = *(const short8*)(wA + (size_t)(t*C3 + ct*16)*C2 + s*32);
      LDA(0) LDA(1) LDA(2) LDA(3)
#define MM(lt,ct) acc##lt##ct = __builtin_amdgcn_mfma_f32_16x16x32_bf16(av##ct, bv##lt, acc##lt##ct, 0, 0, 0);
      TILES(MM)
#undef LDB
#undef LDA
    }
  }
  // fused stats: per (ct,r) sum over this wave's 64 l values
  int pidx = b*8 + blk*2 + lh;
  #pragma unroll
  for (int ct=0;ct<4;ct++){
    float s0=0.f,s1=0.f,s2=0.f,s3=0.f,q0=0.f,q1=0.f,q2=0.f,q3=0.f;
#define ACCST(lt,CT) if (CT == ct){ int l_ = l0 + lt*16 + ln; if (l_ < LEN3){ \
      s0 += acc##lt##CT[0]; q0 = fmaf(acc##lt##CT[0], acc##lt##CT[0], q0); \
      s1 += acc##lt##CT[1]; q1 = fmaf(acc##lt##CT[1], acc##lt##CT[1], q1); \
      s2 += acc##lt##CT[2]; q2 = fmaf(acc##lt##CT[2], acc##lt##CT[2], q2); \
      s3 += acc##lt##CT[3]; q3 = fmaf(acc##lt##CT[3], acc##lt##CT[3], q3); } }
    TILES(ACCST)
#undef ACCST
    RED4L(s0) RED4L(s1) RED4L(s2) RED4L(s3)
    RED4L(q0) RED4L(q1) RED4L(q2) RED4L(q3)
    if (ln == 0){
      int c0 = cbase + ct*16 + kq*4;
      ps[(size_t)(c0+0)*NPART + pidx] = s0;  pq[(size_t)(c0+0)*NPART + pidx] = q0;
      ps[(size_t)(c0+1)*NPART + pidx] = s1;  pq[(size_t)(c0+1)*NPART + pidx] = q1;
      ps[(size_t)(c0+2)*NPART + pidx] = s2;  pq[(size_t)(c0+2)*NPART + pidx] = q2;
      ps[(size_t)(c0+3)*NPART + pidx] = s3;  pq[(size_t)(c0+3)*NPART + pidx] = q3;
    }
  }
}

// ---------------- K9: conv3 recompute (same staged h2) + bn3 + relu + mean -> out (atomic accumulate) ----------------
__global__ __launch_bounds__(256) void k_out3(float* __restrict__ out, const float* __restrict__ b3,
                                              const float* __restrict__ ws){
  const short* pmB = (const short*)(ws + OFF_PM);
  const float* st2 = ws + OFF_S2;
  const short* w3b = (const short*)(ws + OFF_W3B);
  const float* st  = ws + OFF_S3;
  int b   = blockIdx.y;
  int blk = blockIdx.x;
  int l0blk = blk*128;
  __shared__ __align__(16) short sh[130*SROW3];
  STAGE3(sh, b, l0blk)
  __syncthreads();
  int wid = __builtin_amdgcn_readfirstlane(threadIdx.x >> 6);
  int lane = threadIdx.x & 63;
  int ln = lane & 15, kq = lane >> 4;
  int lh = wid & 1, ch = wid >> 1;
  int l0 = l0blk + lh*64;
  int cbase = ch*64;
  DECLBIAS(b3,0) DECLBIAS(b3,1) DECLBIAS(b3,2) DECLBIAS(b3,3)
  TILES(DECLACC)
  const short* hL = sh + (size_t)(lh*64 + ln)*SROW3 + kq*8;
  const short* wA = w3b + (size_t)(cbase + ln)*C2 + kq*8;
  #pragma unroll
  for (int t=0;t<3;t++){
    #pragma unroll
    for (int s=0;s<2;s++){
#define LDB(lt) short8 bv##lt = *(const short8*)(hL + (size_t)(lt*16 + t)*SROW3 + s*32);
      LDB(0) LDB(1) LDB(2) LDB(3)
#define LDA(ct) short8 av##ct = *(const short8*)(wA + (size_t)(t*C3 + ct*16)*C2 + s*32);
      LDA(0) LDA(1) LDA(2) LDA(3)
      TILES(MM)
#undef LDB
#undef LDA
    }
  }
  // bn3 + relu + sum over l (this wave's slice), scaled by 1/511, atomically accumulated
  const float inv = 1.0f/511.0f;
  #pragma unroll
  for (int ct=0;ct<4;ct++){
    int c0 = cbase + ct*16 + kq*4;
    float a0 = st[c0+0], a1 = st[c0+1], a2 = st[c0+2], a3 = st[c0+3];
    float h0 = st[C3+c0+0], h1_ = st[C3+c0+1], h2_ = st[C3+c0+2], h3 = st[C3+c0+3];
    float s0=0.f,s1=0.f,s2=0.f,s3=0.f;
#define OSUM(lt,CT) if (CT == ct){ int l_ = l0 + lt*16 + ln; if (l_ < LEN3){ \
      s0 += fmaxf(fmaf(a0, acc##lt##CT[0], h0 ), 0.f); \
      s1 += fmaxf(fmaf(a1, acc##lt##CT[1], h1_), 0.f); \
      s2 += fmaxf(fmaf(a2, acc##lt##CT[2], h2_), 0.f); \
      s3 += fmaxf(fmaf(a3, acc##lt##CT[3], h3 ), 0.f); } }
    TILES(OSUM)
#undef OSUM
    RED4L(s0) RED4L(s1) RED4L(s2) RED4L(s3)
    if (ln == 0){
      atomicAdd(out + (size_t)b*C3 + c0+0, s0*inv);
      atomicAdd(out + (size_t)b*C3 + c0+1, s1*inv);
      atomicAdd(out + (size_t)b*C3 + c0+2, s2*inv);
      atomicAdd(out + (size_t)b*C3 + c0+3, s3*inv);
    }
  }
}

extern "C" void kernel_launch(void* const* d_in, const int* in_sizes, int n_in,
                              void* d_out, int out_size, void* d_ws, size_t ws_size,
                              hipStream_t stream) {
  const float* x   = (const float*)d_in[0];
  const float* c1w = (const float*)d_in[1];
  const float* c1b = (const float*)d_in[2];
  const float* w1  = (const float*)d_in[3];
  const float* b1  = (const float*)d_in[4];
  const float* g1  = (const float*)d_in[5];
  const float* be1 = (const float*)d_in[6];
  const float* w2  = (const float*)d_in[7];
  const float* b2  = (const float*)d_in[8];
  const float* g2  = (const float*)d_in[9];
  const float* be2 = (const float*)d_in[10];
  const float* w3  = (const float*)d_in[11];
  const float* b3  = (const float*)d_in[12];
  const float* g3  = (const float*)d_in[13];
  const float* be3 = (const float*)d_in[14];
  float* ws  = (float*)d_ws;
  float* out = (float*)d_out;

  hipLaunchKernelGGL(k_pp,     dim3(8*NB + 8*NP + 96), dim3(256), 0, stream, x, c1b, c1w, w2, w3, ws);
  hipLaunchKernelGGL(k_gemm,   dim3(64,8), dim3(256), 0, stream, ws);
  hipLaunchKernelGGL(k_conv1f, dim3(8,NB), dim3(256), 0, stream, w1, b1, ws);
  hipLaunchKernelGGL(k_fin,    dim3(C1), dim3(256), 0, stream, ws+OFF_PS, ws+OFF_PQ, g1, be1, ws+OFF_S1, C1, NPART, 1.0/((double)NB*LEN1), (float*)nullptr);
  hipLaunchKernelGGL(k_conv2m, dim3(4,NB), dim3(256), 0, stream, b2, ws);
  hipLaunchKernelGGL(k_fin,    dim3(C2), dim3(256), 0, stream, ws+OFF_PS, ws+OFF_PQ, g2, be2, ws+OFF_S2, C2, NPART2, 1.0/((double)NB*LEN2), (float*)nullptr);
  hipLaunchKernelGGL(k_conv3s, dim3(4,NB), dim3(256), 0, stream, b3, ws);
  hipLaunchKernelGGL(k_fin,    dim3(C3), dim3(256), 0, stream, ws+OFF_PS, ws+OFF_PQ, g3, be3, ws+OFF_S3, C3, NPART, 1.0/((double)NB*LEN3), out);
  hipLaunchKernelGGL(k_out3,   dim3(4,NB), dim3(256), 0, stream, out, b3, ws);
}

// Round 17
// 258.233 us; speedup vs baseline: 1.0481x; 1.0481x over previous
//
#include <hip/hip_runtime.h>
#include <math.h>

#define NB 256
#define SEQ 65536
#define NP 2047
#define NPM 2046
#define NPP 2048   // x3 row stride (padded so rows are 16B-aligned for float4 loads)
#define KPAD 2048  // gemm K padded (bf16 operands zero-filled at k=2046,2047)
#define LEN1 2047
#define LEN2 1023
#define LEN3 511
#define C1 32
#define C2 64
#define C3 128
#define NPART 2048
#define NPART2 (NB*4)   // layer-2 partial count (dense stride — MUST match k_fin npart)
#define SROW 40     // conv2m LDS row stride (shorts): 80 B -> 16B-aligned rows, bank-spread
#define SROW3 72    // conv3 LDS row stride (shorts): 144 B -> 16B-aligned rows, bank-spread

// workspace offsets (floats). Region timeline:
//   Y2: Wb (bf16, dead after gemm) -> h1rB bf16 [b][m][i] raw pooled (conv1f out, dead after conv2m)
//   Y1: pmB bf16 [b][m][c] raw pooled conv2 out at OFF_PM (read by conv3s AND out3, bn2 applied on stage)
//   DMAX: dmax bf16 [b][KPAD]
#define OFF_X3   0
#define SZ_X3    (NB*3*NPP)
#define OFF_DMAX (OFF_X3 + SZ_X3)
#define SZ_DMAX  (NB*NPM)
#define OFF_Y1   (OFF_DMAX + SZ_DMAX)
#define SZ_Y1    (NB*C1*LEN1)
#define OFF_Y2   (OFF_Y1 + SZ_Y1)
#define SZ_Y2    (NB*C2*LEN2)
#define OFF_S1   (OFF_Y2 + SZ_Y2)
#define OFF_S2   (OFF_S1 + 2*C1)
#define OFF_S3   (OFF_S2 + 2*C2)
#define OFF_W2C  (OFF_S3 + 2*C3)
#define OFF_W3B  (OFF_W2C + C1*C2*3)   // conv3 weights bf16 [tap][c][i]
#define OFF_PS   (OFF_W3B + C2*C3*3)
#define OFF_PQ   (OFF_PS + C3*NPART)
#define OFF_WB   OFF_Y2   // gemm W bf16 [NP][KPAD] (dead after gemm)
#define OFF_H1R  OFF_Y2   // pooled raw conv1 bf16 [b][m][i] (dead after conv2m)
#define OFF_PM   (OFF_Y1 + 4300000)   // bf16 [b][m][c], m<LEN3 (8.37M shorts = 4.19M floats, fits)
#define OFF_W2B  OFF_W2C  // conv2 weights bf16 [tap][c=64][i=32]

typedef __attribute__((ext_vector_type(8))) short short8;
typedef __attribute__((ext_vector_type(4))) short short4v;
typedef __attribute__((ext_vector_type(4))) float f32x4;

__device__ inline short f2bf(float f){
  union { float f; unsigned u; } x; x.f = f;
  unsigned r = x.u + 0x7FFF + ((x.u >> 16) & 1);   // RNE; inputs are normal finite
  return (short)(r >> 16);
}
__device__ inline float bf2f(short s){
  union { unsigned u; float f; } x; x.u = ((unsigned)(unsigned short)s) << 16; return x.f;
}

#define RED4L(v) v += __shfl_xor(v,1,64); v += __shfl_xor(v,2,64); \
                 v += __shfl_xor(v,4,64); v += __shfl_xor(v,8,64);

// MFMA tile grid: (lt, ct) in 4x4
#define TILES(X) X(0,0) X(0,1) X(0,2) X(0,3) X(1,0) X(1,1) X(1,2) X(1,3) \
                 X(2,0) X(2,1) X(2,2) X(2,3) X(3,0) X(3,1) X(3,2) X(3,3)
#define DECLBIAS(P,ct) f32x4 bi##ct = *(const f32x4*)((P) + cbase + ct*16 + kq*4);
#define DECLACC(lt,ct) f32x4 acc##lt##ct = bi##ct;

// ---------------- K1: merged patch (mean/std/dmax/x3) + prep (weight packs) ----------------
__global__ __launch_bounds__(256) void k_pp(const float* __restrict__ x, const float* __restrict__ c1b,
                                            const float* __restrict__ W, const float* __restrict__ w2,
                                            const float* __restrict__ w3, float* __restrict__ ws){
  int bid = blockIdx.x;
  if (bid < 32*NB){
    // ---- patch branch (proven R0 structure; x3 rows stride NPP) ----
    float* x3    = ws + OFF_X3;
    short* dmaxB = (short*)(ws + OFF_DMAX);   // bf16 [NB][KPAD], zero-padded k>=NPM
    int b = bid >> 5;
    int chunk = bid & 31;              // 0..31, 2048 floats each
    const float* xr = x + (size_t)b*SEQ + chunk*2048;
    __shared__ float Ss[65], Qs[65], Dm[65];
    int w = threadIdx.x >> 6;
    int l = threadIdx.x & 63;
    #pragma unroll
    for (int i=0;i<2;i++){
      int seg = w*2 + i;
      int off = seg*256;
      float4 A = *(const float4*)(xr + off + l*4);
      float4 Bh = make_float4(0.f,0.f,0.f,0.f);
      if (l >= 56){
        int g = chunk*2048 + off + 256 + (l-56)*4;
        if (g + 3 < SEQ) Bh = *(const float4*)(xr + off + 256 + (l-56)*4);
      }
      int src = (l+8) & 63;
      float p0 = __shfl(A.x, src, 64), p1 = __shfl(A.y, src, 64),
            p2 = __shfl(A.z, src, 64), p3 = __shfl(A.w, src, 64);
      if (l >= 56){ p0=Bh.x; p1=Bh.y; p2=Bh.z; p3=Bh.w; }
      float s = (A.x+A.y)+(A.z+A.w);
      float q = fmaf(A.x,A.x, fmaf(A.y,A.y, fmaf(A.z,A.z, A.w*A.w)));
      float d = fmaxf(fmaxf(p0-A.x, p1-A.y), fmaxf(p2-A.z, p3-A.w));
      #pragma unroll
      for (int o=1;o<8;o<<=1){
        s += __shfl_xor(s,o,64);
        q += __shfl_xor(q,o,64);
        d  = fmaxf(d, __shfl_xor(d,o,64));
      }
      if ((l&7)==0){ int m = seg*8 + (l>>3); Ss[m]=s; Qs[m]=q; Dm[m]=d; }
    }
    if (w==0){
      float s=0.f,q=0.f,d=-1e30f;
      if (l < 8){
        int g = chunk*2048 + 2048 + l*4;
        if (g+3 < SEQ){
          float4 A = *(const float4*)(xr + 2048 + l*4);
          float4 P = make_float4(0.f,0.f,0.f,0.f);
          if (g+35 < SEQ) P = *(const float4*)(xr + 2048 + 32 + l*4);
          s = (A.x+A.y)+(A.z+A.w);
          q = fmaf(A.x,A.x, fmaf(A.y,A.y, fmaf(A.z,A.z, A.w*A.w)));
          d = fmaxf(fmaxf(P.x-A.x, P.y-A.y), fmaxf(P.z-A.z, P.w-A.w));
        }
      }
      #pragma unroll
      for (int o=1;o<8;o<<=1){
        s += __shfl_xor(s,o,64);
        q += __shfl_xor(q,o,64);
        d  = fmaxf(d, __shfl_xor(d,o,64));
      }
      if (l==0){ Ss[64]=s; Qs[64]=q; Dm[64]=d; }
    }
    __syncthreads();
    if (threadIdx.x < 64){
      int j = threadIdx.x;
      int p = chunk*64 + j;                 // 0..2047
      if (p < NP){
        float S = Ss[j]+Ss[j+1];
        float Q = Qs[j]+Qs[j+1];
        float mean = S*(1.0f/64.0f);
        float var  = (Q - S*mean)*(1.0f/63.0f);   // ddof=1
        x3[(size_t)(b*3+0)*NPP + p] = mean;
        x3[(size_t)(b*3+1)*NPP + p] = sqrtf(fmaxf(var,0.0f));
        x3[(size_t)(b*3+2)*NPP + p] = c1b[p];     // bias init (gemm atomically adds on top)
      }
      dmaxB[(size_t)b*KPAD + p] = (p < NPM) ? f2bf(fmaxf(Dm[j], Dm[j+1])) : (short)0;
    }
  } else {
    // ---- prep branch ----
    int pb = bid - 32*NB;
    if (pb < 8*NP){
      short* Wb = (short*)(ws + OFF_WB);
      int o = pb >> 3;
      int k = (pb & 7)*256 + threadIdx.x;
      Wb[(size_t)o*KPAD + k] = (k < NPM) ? f2bf(W[(size_t)o*NPM + k]) : (short)0;
    } else {
      short* w2b = (short*)(ws + OFF_W2B);
      short* w3b = (short*)(ws + OFF_W3B);
      int t = (pb - 8*NP)*256 + threadIdx.x;
      if (t < 3*C2*C1){                        // 6144
        int tap = t / (C2*C1);
        int r = t - tap*(C2*C1);
        int c = r >> 5, i = r & 31;
        w2b[t] = f2bf(w2[(c*C1 + i)*3 + tap]); // w2b[(tap*C2+c)*C1+i]
      }
      if (t < 3*C3*C2){                        // 24576
        int tap = t / (C3*C2);
        int r = t - tap*(C3*C2);
        int c = r / C2, i = r - c*C2;
        w3b[(tap*C3 + c)*C2 + i] = f2bf(w3[(c*C2+i)*3 + tap]);
      }
    }
  }
}

// ---------------- K2: d2[b,o] += sum_k dmax[b,k]*W[o,k] via MFMA bf16 ----------------
__global__ __launch_bounds__(256) void k_gemm(float* __restrict__ ws){
  const short* Ab = (const short*)(ws + OFF_DMAX); // [NB][KPAD]
  const short* Bb = (const short*)(ws + OFF_WB);   // [NP][KPAD]
  float* x3 = ws + OFF_X3;
  int wid  = __builtin_amdgcn_readfirstlane(threadIdx.x >> 6);
  int lane = threadIdx.x & 63;
  int ln = lane & 15, kq = lane >> 4;
  int n0  = blockIdx.x*32;                 // o tile pair base
  int ks  = blockIdx.y*512;                // K split (16 steps of 32)
  f32x4 acc[4][2];
  #pragma unroll
  for (int bt=0;bt<4;bt++){ acc[bt][0] = (f32x4){0.f,0.f,0.f,0.f}; acc[bt][1] = (f32x4){0.f,0.f,0.f,0.f}; }
  int o0 = n0 + ln, o1 = n0 + 16 + ln;
  const short* ap  = Ab + (size_t)(wid*16 + ln)*KPAD + ks + kq*8;   // + bt*64*KPAD
  const short* bp0 = Bb + (size_t)min(o0, NP-1)*KPAD + ks + kq*8;
  const short* bp1 = Bb + (size_t)min(o1, NP-1)*KPAD + ks + kq*8;
  #pragma unroll 2
  for (int s=0; s<16; s++){
    short8 b0 = *(const short8*)(bp0 + s*32);
    short8 b1 = *(const short8*)(bp1 + s*32);
    #pragma unroll
    for (int bt=0;bt<4;bt++){
      short8 av = *(const short8*)(ap + (size_t)bt*64*KPAD + s*32);
      acc[bt][0] = __builtin_amdgcn_mfma_f32_16x16x32_bf16(av, b0, acc[bt][0], 0, 0, 0);
      acc[bt][1] = __builtin_amdgcn_mfma_f32_16x16x32_bf16(av, b1, acc[bt][1], 0, 0, 0);
    }
  }
  // D[row=kq*4+r][col=ln]: row -> b offset, col -> o offset
  #pragma unroll
  for (int bt=0;bt<4;bt++){
    #pragma unroll
    for (int r=0;r<4;r++){
      int b = bt*64 + wid*16 + kq*4 + r;
      float* xp = x3 + ((size_t)(b*3) + 2)*NPP;
      if (o0 < NP) atomicAdd(xp + o0, acc[bt][0][r]);
      if (o1 < NP) atomicAdd(xp + o1, acc[bt][1][r]);
    }
  }
}

// ---------------- K3: conv1f (3->32, k=5, pad=2) + fused BN1 stats + fused maxpool ----------------
// pooled raw output stored bf16 (h1rB) — halves the h1 round-trip (stats still from fp32 accs).
__global__ __launch_bounds__(256) void k_conv1f(const float* __restrict__ w1, const float* __restrict__ b1, float* __restrict__ ws){
  const float* x3 = ws + OFF_X3;
  short* h1rB = (short*)(ws + OFF_H1R);  // bf16 raw pooled [b][m][c], m<LEN2
  float* ps = ws + OFF_PS;
  float* pq = ws + OFF_PQ;
  int b = blockIdx.y;
  int blk = blockIdx.x;                 // 0..7 (256 positions per block)
  int w = threadIdx.x >> 6;             // wave 0..3 (64 positions)
  int lane = threadIdx.x & 63;
  int h = lane >> 5, c = lane & 31;     // half-wave position block, channel
  int p0 = blk*256 + w*64 + h*32;       // this lane's 32 positions: p0..p0+31
  float wv[3][5];
  #pragma unroll
  for (int i=0;i<3;i++){
    #pragma unroll
    for (int j=0;j<5;j++) wv[i][j] = w1[(c*3+i)*5+j];
  }
  float bc = b1[c];
  const float* xb = x3 + (size_t)b*3*NPP;
  float s = 0.f, q = 0.f;
  #pragma unroll
  for (int k0=0;k0<32;k0+=8){
    int base = p0 + k0 - 4;             // multiple of 4 (may be -4 at the very start)
    float xw[3][16];
    #pragma unroll
    for (int i=0;i<3;i++){
      const float* xr = xb + (size_t)i*NPP;
      if (base >= 0 && base + 16 <= LEN1){
        #pragma unroll
        for (int t=0;t<4;t++) *(f32x4*)&xw[i][4*t] = *(const f32x4*)(xr + base + 4*t);
      } else {
        #pragma unroll
        for (int t=0;t<16;t++){ int g = base + t; xw[i][t] = (g >= 0 && g < LEN1) ? xr[g] : 0.f; }
      }
    }
    float acc[8];
    #pragma unroll
    for (int k=0;k<8;k++){
      float a = bc;
      #pragma unroll
      for (int i=0;i<3;i++){
        #pragma unroll
        for (int j=0;j<5;j++) a = fmaf(wv[i][j], xw[i][k+j+2], a);   // g = p0+k0+k+j-2 -> t=k+j+2
      }
      acc[k] = a;
      if (p0 + k0 + k < LEN1){ s += a; q = fmaf(a, a, q); }   // stats over UNPOOLED y1
    }
    #pragma unroll
    for (int t=0;t<4;t++){
      int m = ((p0 + k0) >> 1) + t;
      if (m < LEN2) h1rB[((size_t)b*LEN2 + m)*C1 + c] = f2bf(fmaxf(acc[2*t], acc[2*t+1]));
    }
  }
  s += __shfl_xor(s, 32, 64);
  q += __shfl_xor(q, 32, 64);
  __shared__ float es[4][C1], eq[4][C1];
  if (h == 0){ es[w][c] = s; eq[w][c] = q; }
  __syncthreads();
  if (threadIdx.x < C1){
    int cc = threadIdx.x;
    float S = es[0][cc]+es[1][cc]+es[2][cc]+es[3][cc];
    float Q = eq[0][cc]+eq[1][cc]+eq[2][cc]+eq[3][cc];
    ps[(size_t)cc*NPART + b*8 + blk] = S;
    pq[(size_t)cc*NPART + b*8 + blk] = Q;
  }
}

// ---------------- finalize BN from partials (+ optional out-zeroing for layer 3) ----------------
__global__ __launch_bounds__(256) void k_fin(const float* __restrict__ ps, const float* __restrict__ pq,
                                             const float* __restrict__ g, const float* __restrict__ be,
                                             float* __restrict__ stats, int C, int npart, double invN,
                                             float* __restrict__ outz){
  if (outz) outz[(size_t)threadIdx.x * C3 + blockIdx.x] = 0.f;  // layer-3: 128 blocks x 256 thr = NB*C3
  int c = blockIdx.x;
  double s=0.0, q=0.0;
  for (int j=threadIdx.x; j<npart; j+=256){ s += (double)ps[c*npart+j]; q += (double)pq[c*npart+j]; }
  #pragma unroll
  for (int off=32; off; off>>=1){ s += __shfl_xor(s,off,64); q += __shfl_xor(q,off,64); }
  __shared__ double rs[4], rq[4];
  int wid = threadIdx.x>>6, lane=threadIdx.x&63;
  if (lane==0){ rs[wid]=s; rq[wid]=q; }
  __syncthreads();
  if (threadIdx.x==0){
    double S = rs[0]+rs[1]+rs[2]+rs[3];
    double Q = rq[0]+rq[1]+rq[2]+rq[3];
    double mean = S*invN;
    double var  = Q*invN - mean*mean;
    double a = (double)g[c] / sqrt(var + 1e-5);
    stats[c]   = (float)a;
    stats[C+c] = (float)((double)be[c] - mean*a);
  }
}

// ---------------- K5: conv2m — LDS-staged h1 tile (bn1 applied to bf16 input); pmax stored bf16 ----------------
__global__ __launch_bounds__(256) void k_conv2m(const float* __restrict__ b2, float* __restrict__ ws){
  const short* h1rB = (const short*)(ws + OFF_H1R); // bf16 [b][m][C1] raw pooled
  const float* st1 = ws + OFF_S1;                   // bn1 a[32], b[32]
  const short* w2b = (const short*)(ws + OFF_W2B);  // [tap][C2][C1]
  short* pmB = (short*)(ws + OFF_PM);               // bf16 [b][m][c], m<LEN3 (raw pooled, pre-bn2)
  float* ps = ws + OFF_PS;
  float* pq = ws + OFF_PQ;
  int b   = blockIdx.y;
  int blk = blockIdx.x;                // 0..3 (256 positions each)
  int l0  = blk*256;
  __shared__ __align__(16) short sh[258*SROW];
  // ---- stage: 258 rows x 4 groups(8ch); consecutive threads -> consecutive 16B chunks (coalesced)
  for (int u = threadIdx.x; u < 258*4; u += 256){
    int row = u >> 2, g = u & 3;
    int pos = l0 - 1 + row;
    short8 r8 = (short8)0;
    if (pos >= 0 && pos < LEN2){
      short8 xv = *(const short8*)(h1rB + ((size_t)b*LEN2 + pos)*C1 + g*8);
      f32x4 alo = *(const f32x4*)(st1 + g*8),      ahi = *(const f32x4*)(st1 + g*8 + 4);
      f32x4 blo = *(const f32x4*)(st1 + C1 + g*8), bhi = *(const f32x4*)(st1 + C1 + g*8 + 4);
      #pragma unroll
      for (int j=0;j<4;j++){
        r8[j]   = f2bf(fmaxf(fmaf(alo[j], bf2f(xv[j]),   blo[j]), 0.f));
        r8[j+4] = f2bf(fmaxf(fmaf(ahi[j], bf2f(xv[j+4]), bhi[j]), 0.f));
      }
    }
    *(short8*)(sh + row*SROW + g*8) = r8;
  }
  __syncthreads();
  int w   = __builtin_amdgcn_readfirstlane(threadIdx.x >> 6);
  int lane = threadIdx.x & 63;
  int ln = lane & 15, kq = lane >> 4;
  int lw = l0 + w*64;                  // wave's position base; l = lw + lt*16 + ln
  int cbase = 0;
  DECLBIAS(b2,0) DECLBIAS(b2,1) DECLBIAS(b2,2) DECLBIAS(b2,3)
  TILES(DECLACC)
  // preload 12 A fragments (tap x ct)
  const short* wA = w2b + (size_t)ln*C1 + kq*8;
#define LDW(T,ct) short8 aw##T##ct = *(const short8*)(wA + (size_t)(T*C2 + ct*16)*C1);
  LDW(0,0) LDW(0,1) LDW(0,2) LDW(0,3)
  LDW(1,0) LDW(1,1) LDW(1,2) LDW(1,3)
  LDW(2,0) LDW(2,1) LDW(2,2) LDW(2,3)
#undef LDW
#define MMT0(lt,ct) acc##lt##ct = __builtin_amdgcn_mfma_f32_16x16x32_bf16(aw0##ct, bv##lt, acc##lt##ct, 0, 0, 0);
#define MMT1(lt,ct) acc##lt##ct = __builtin_amdgcn_mfma_f32_16x16x32_bf16(aw1##ct, bv##lt, acc##lt##ct, 0, 0, 0);
#define MMT2(lt,ct) acc##lt##ct = __builtin_amdgcn_mfma_f32_16x16x32_bf16(aw2##ct, bv##lt, acc##lt##ct, 0, 0, 0);
#define LDB2(lt,T) short8 bv##lt = *(const short8*)(sh + (size_t)(w*64 + lt*16 + T + ln)*SROW + kq*8);
#define CSTEP(T) { LDB2(0,T) LDB2(1,T) LDB2(2,T) LDB2(3,T) TILES(MMT##T) }
  CSTEP(0) CSTEP(1) CSTEP(2)
#undef CSTEP
#undef LDB2
  // pool (lane pairs along ln) + store bf16 short4 at [b][m][ct*16+kq*4]
#define PST(lt,ct) { \
    float p0_ = fmaxf(acc##lt##ct[0], __shfl_xor(acc##lt##ct[0],1,64)); \
    float p1_ = fmaxf(acc##lt##ct[1], __shfl_xor(acc##lt##ct[1],1,64)); \
    float p2_ = fmaxf(acc##lt##ct[2], __shfl_xor(acc##lt##ct[2],1,64)); \
    float p3_ = fmaxf(acc##lt##ct[3], __shfl_xor(acc##lt##ct[3],1,64)); \
    int l_ = lw + lt*16 + ln; \
    if (!(ln & 1) && (l_ >> 1) < LEN3){ \
      short4v pv_ = { f2bf(p0_), f2bf(p1_), f2bf(p2_), f2bf(p3_) }; \
      *(short4v*)(pmB + ((size_t)b*LEN3 + (l_>>1))*C2 + ct*16 + kq*4) = pv_; } }
  TILES(PST)
#undef PST
  // fused stats over unpooled positions (mask l<LEN2)
  __shared__ float es[4][C2], eq[4][C2];
  #pragma unroll
  for (int ct=0;ct<4;ct++){
    float s0=0.f,s1=0.f,s2=0.f,s3=0.f,q0=0.f,q1=0.f,q2=0.f,q3=0.f;
#define ACCST(lt,CT) if (CT == ct){ int l_ = lw + lt*16 + ln; if (l_ < LEN2){ \
      s0 += acc##lt##CT[0]; q0 = fmaf(acc##lt##CT[0], acc##lt##CT[0], q0); \
      s1 += acc##lt##CT[1]; q1 = fmaf(acc##lt##CT[1], acc##lt##CT[1], q1); \
      s2 += acc##lt##CT[2]; q2 = fmaf(acc##lt##CT[2], acc##lt##CT[2], q2); \
      s3 += acc##lt##CT[3]; q3 = fmaf(acc##lt##CT[3], acc##lt##CT[3], q3); } }
    TILES(ACCST)
#undef ACCST
    RED4L(s0) RED4L(s1) RED4L(s2) RED4L(s3)
    RED4L(q0) RED4L(q1) RED4L(q2) RED4L(q3)
    if (ln == 0){
      int c0 = ct*16 + kq*4;
      es[w][c0+0]=s0; es[w][c0+1]=s1; es[w][c0+2]=s2; es[w][c0+3]=s3;
      eq[w][c0+0]=q0; eq[w][c0+1]=q1; eq[w][c0+2]=q2; eq[w][c0+3]=q3;
    }
  }
  __syncthreads();
  if (threadIdx.x < C2){
    int c = threadIdx.x;
    float S = es[0][c]+es[1][c]+es[2][c]+es[3][c];
    float Q = eq[0][c]+eq[1][c]+eq[2][c]+eq[3][c];
    ps[(size_t)c*NPART2 + b*4 + blk] = S;
    pq[(size_t)c*NPART2 + b*4 + blk] = Q;
  }
}

// ---- shared staging for conv3s/out3: pmB window -> LDS bf16 [130][SROW3], bn2+relu+f2bf fused ----
#define STAGE3(SH, BB, L0BLK) \
  for (int u = threadIdx.x; u < 130*8; u += 256){ \
    int row_ = u >> 3, g_ = u & 7; \
    int pos_ = (L0BLK) - 1 + row_; \
    short8 r8_ = (short8)0; \
    if (pos_ >= 0 && pos_ < LEN3){ \
      short8 xm_ = *(const short8*)(pmB + ((size_t)(BB)*LEN3 + pos_)*C2 + g_*8); \
      f32x4 alo_ = *(const f32x4*)(st2 + g_*8),      ahi_ = *(const f32x4*)(st2 + g_*8 + 4); \
      f32x4 blo_ = *(const f32x4*)(st2 + C2 + g_*8), bhi_ = *(const f32x4*)(st2 + C2 + g_*8 + 4); \
      _Pragma("unroll") \
      for (int j=0;j<4;j++){ \
        r8_[j]   = f2bf(fmaxf(fmaf(alo_[j], bf2f(xm_[j]),   blo_[j]), 0.f)); \
        r8_[j+4] = f2bf(fmaxf(fmaf(ahi_[j], bf2f(xm_[j+4]), bhi_[j]), 0.f)); \
      } \
    } \
    *(short8*)(SH + (size_t)row_*SROW3 + g_*8) = r8_; \
  }

// ---------------- K7: conv3 via MFMA bf16 — STATS ONLY; h2 built on-the-fly from pmB ----------------
__global__ __launch_bounds__(256) void k_conv3s(const float* __restrict__ b3, float* __restrict__ ws){
  const short* pmB = (const short*)(ws + OFF_PM);   // bf16 [b][m][C2] raw pooled
  const float* st2 = ws + OFF_S2;
  const short* w3b = (const short*)(ws + OFF_W3B);  // [tap][C3][C2]
  float* ps = ws + OFF_PS;
  float* pq = ws + OFF_PQ;
  int b   = blockIdx.y;
  int blk = blockIdx.x;                // 0..3 (128 positions)
  int l0blk = blk*128;
  __shared__ __align__(16) short sh[130*SROW3];
  STAGE3(sh, b, l0blk)
  __syncthreads();
  int wid = __builtin_amdgcn_readfirstlane(threadIdx.x >> 6);
  int lane = threadIdx.x & 63;
  int ln = lane & 15, kq = lane >> 4;
  int lh = wid & 1, ch = wid >> 1;     // wave-uniform
  int l0 = l0blk + lh*64;              // l = l0 + lt*16 + ln
  int cbase = ch*64;                   // A-row c = cbase+ct*16+ln; D-row c = cbase+ct*16+kq*4+r
  DECLBIAS(b3,0) DECLBIAS(b3,1) DECLBIAS(b3,2) DECLBIAS(b3,3)
  TILES(DECLACC)
  // fragment (lt,t,s): LDS row = lh*64 + lt*16 + ln + t ; ch = s*32 + kq*8
  const short* hL = sh + (size_t)(lh*64 + ln)*SROW3 + kq*8;
  const short* wA = w3b + (size_t)(cbase + ln)*C2 + kq*8;        // + (t*C3 + ct*16)*C2 + s*32
  #pragma unroll
  for (int t=0;t<3;t++){
    #pragma unroll
    for (int s=0;s<2;s++){
#define LDB(lt) short8 bv##lt = *(const short8*)(hL + (size_t)(lt*16 + t)*SROW3 + s*32);
      LDB(0) LDB(1) LDB(2) LDB(3)
#define LDA(ct) short8 av##ct = *(const short8*)(wA + (size_t)(t*C3 + ct*16)*C2 + s*32);
      LDA(0) LDA(1) LDA(2) LDA(3)
#define MM(lt,ct) acc##lt##ct = __builtin_amdgcn_mfma_f32_16x16x32_bf16(av##ct, bv##lt, acc##lt##ct, 0, 0, 0);
      TILES(MM)
#undef LDB
#undef LDA
    }
  }
  // fused stats: per (ct,r) sum over this wave's 64 l values
  int pidx = b*8 + blk*2 + lh;
  #pragma unroll
  for (int ct=0;ct<4;ct++){
    float s0=0.f,s1=0.f,s2=0.f,s3=0.f,q0=0.f,q1=0.f,q2=0.f,q3=0.f;
#define ACCST(lt,CT) if (CT == ct){ int l_ = l0 + lt*16 + ln; if (l_ < LEN3){ \
      s0 += acc##lt##CT[0]; q0 = fmaf(acc##lt##CT[0], acc##lt##CT[0], q0); \
      s1 += acc##lt##CT[1]; q1 = fmaf(acc##lt##CT[1], acc##lt##CT[1], q1); \
      s2 += acc##lt##CT[2]; q2 = fmaf(acc##lt##CT[2], acc##lt##CT[2], q2); \
      s3 += acc##lt##CT[3]; q3 = fmaf(acc##lt##CT[3], acc##lt##CT[3], q3); } }
    TILES(ACCST)
#undef ACCST
    RED4L(s0) RED4L(s1) RED4L(s2) RED4L(s3)
    RED4L(q0) RED4L(q1) RED4L(q2) RED4L(q3)
    if (ln == 0){
      int c0 = cbase + ct*16 + kq*4;
      ps[(size_t)(c0+0)*NPART + pidx] = s0;  pq[(size_t)(c0+0)*NPART + pidx] = q0;
      ps[(size_t)(c0+1)*NPART + pidx] = s1;  pq[(size_t)(c0+1)*NPART + pidx] = q1;
      ps[(size_t)(c0+2)*NPART + pidx] = s2;  pq[(size_t)(c0+2)*NPART + pidx] = q2;
      ps[(size_t)(c0+3)*NPART + pidx] = s3;  pq[(size_t)(c0+3)*NPART + pidx] = q3;
    }
  }
}

// ---------------- K9: conv3 recompute (same staged h2) + bn3 + relu + mean -> out (atomic accumulate) ----------------
__global__ __launch_bounds__(256) void k_out3(float* __restrict__ out, const float* __restrict__ b3,
                                              const float* __restrict__ ws){
  const short* pmB = (const short*)(ws + OFF_PM);
  const float* st2 = ws + OFF_S2;
  const short* w3b = (const short*)(ws + OFF_W3B);
  const float* st  = ws + OFF_S3;
  int b   = blockIdx.y;
  int blk = blockIdx.x;
  int l0blk = blk*128;
  __shared__ __align__(16) short sh[130*SROW3];
  STAGE3(sh, b, l0blk)
  __syncthreads();
  int wid = __builtin_amdgcn_readfirstlane(threadIdx.x >> 6);
  int lane = threadIdx.x & 63;
  int ln = lane & 15, kq = lane >> 4;
  int lh = wid & 1, ch = wid >> 1;
  int l0 = l0blk + lh*64;
  int cbase = ch*64;
  DECLBIAS(b3,0) DECLBIAS(b3,1) DECLBIAS(b3,2) DECLBIAS(b3,3)
  TILES(DECLACC)
  const short* hL = sh + (size_t)(lh*64 + ln)*SROW3 + kq*8;
  const short* wA = w3b + (size_t)(cbase + ln)*C2 + kq*8;
  #pragma unroll
  for (int t=0;t<3;t++){
    #pragma unroll
    for (int s=0;s<2;s++){
#define LDB(lt) short8 bv##lt = *(const short8*)(hL + (size_t)(lt*16 + t)*SROW3 + s*32);
      LDB(0) LDB(1) LDB(2) LDB(3)
#define LDA(ct) short8 av##ct = *(const short8*)(wA + (size_t)(t*C3 + ct*16)*C2 + s*32);
      LDA(0) LDA(1) LDA(2) LDA(3)
      TILES(MM)
#undef LDB
#undef LDA
    }
  }
  // bn3 + relu + sum over l (this wave's slice), scaled by 1/511, atomically accumulated
  const float inv = 1.0f/511.0f;
  #pragma unroll
  for (int ct=0;ct<4;ct++){
    int c0 = cbase + ct*16 + kq*4;
    float a0 = st[c0+0], a1 = st[c0+1], a2 = st[c0+2], a3 = st[c0+3];
    float h0 = st[C3+c0+0], h1_ = st[C3+c0+1], h2_ = st[C3+c0+2], h3 = st[C3+c0+3];
    float s0=0.f,s1=0.f,s2=0.f,s3=0.f;
#define OSUM(lt,CT) if (CT == ct){ int l_ = l0 + lt*16 + ln; if (l_ < LEN3){ \
      s0 += fmaxf(fmaf(a0, acc##lt##CT[0], h0 ), 0.f); \
      s1 += fmaxf(fmaf(a1, acc##lt##CT[1], h1_), 0.f); \
      s2 += fmaxf(fmaf(a2, acc##lt##CT[2], h2_), 0.f); \
      s3 += fmaxf(fmaf(a3, acc##lt##CT[3], h3 ), 0.f); } }
    TILES(OSUM)
#undef OSUM
    RED4L(s0) RED4L(s1) RED4L(s2) RED4L(s3)
    if (ln == 0){
      atomicAdd(out + (size_t)b*C3 + c0+0, s0*inv);
      atomicAdd(out + (size_t)b*C3 + c0+1, s1*inv);
      atomicAdd(out + (size_t)b*C3 + c0+2, s2*inv);
      atomicAdd(out + (size_t)b*C3 + c0+3, s3*inv);
    }
  }
}

extern "C" void kernel_launch(void* const* d_in, const int* in_sizes, int n_in,
                              void* d_out, int out_size, void* d_ws, size_t ws_size,
                              hipStream_t stream) {
  const float* x   = (const float*)d_in[0];
  const float* c1w = (const float*)d_in[1];
  const float* c1b = (const float*)d_in[2];
  const float* w1  = (const float*)d_in[3];
  const float* b1  = (const float*)d_in[4];
  const float* g1  = (const float*)d_in[5];
  const float* be1 = (const float*)d_in[6];
  const float* w2  = (const float*)d_in[7];
  const float* b2  = (const float*)d_in[8];
  const float* g2  = (const float*)d_in[9];
  const float* be2 = (const float*)d_in[10];
  const float* w3  = (const float*)d_in[11];
  const float* b3  = (const float*)d_in[12];
  const float* g3  = (const float*)d_in[13];
  const float* be3 = (const float*)d_in[14];
  float* ws  = (float*)d_ws;
  float* out = (float*)d_out;

  hipLaunchKernelGGL(k_pp,     dim3(32*NB + 8*NP + 96), dim3(256), 0, stream, x, c1b, c1w, w2, w3, ws);
  hipLaunchKernelGGL(k_gemm,   dim3(64,4), dim3(256), 0, stream, ws);
  hipLaunchKernelGGL(k_conv1f, dim3(8,NB), dim3(256), 0, stream, w1, b1, ws);
  hipLaunchKernelGGL(k_fin,    dim3(C1), dim3(256), 0, stream, ws+OFF_PS, ws+OFF_PQ, g1, be1, ws+OFF_S1, C1, NPART, 1.0/((double)NB*LEN1), (float*)nullptr);
  hipLaunchKernelGGL(k_conv2m, dim3(4,NB), dim3(256), 0, stream, b2, ws);
  hipLaunchKernelGGL(k_fin,    dim3(C2), dim3(256), 0, stream, ws+OFF_PS, ws+OFF_PQ, g2, be2, ws+OFF_S2, C2, NPART2, 1.0/((double)NB*LEN2), (float*)nullptr);
  hipLaunchKernelGGL(k_conv3s, dim3(4,NB), dim3(256), 0, stream, b3, ws);
  hipLaunchKernelGGL(k_fin,    dim3(C3), dim3(256), 0, stream, ws+OFF_PS, ws+OFF_PQ, g3, be3, ws+OFF_S3, C3, NPART, 1.0/((double)NB*LEN3), out);
  hipLaunchKernelGGL(k_out3,   dim3(4,NB), dim3(256), 0, stream, out, b3, ws);
}